// Round 13
// baseline (645.150 us; speedup 1.0000x reference)
//
#include <hip/hip_runtime.h>

#define NN 50000
#define EE 800000
#define GG 512
#define NP 50048   // NN padded to multiple of 64
#define EB 3125    // edge blocks of 256
#define SCB 196    // scan blocks of 256 covering NN

typedef short bf16x8 __attribute__((ext_vector_type(8)));
typedef float floatx4 __attribute__((ext_vector_type(4)));

__device__ inline unsigned short f2b(float f) {
    unsigned u = __float_as_uint(f);
    unsigned r = (u + 0x7fffu + ((u >> 16) & 1u)) >> 16;
    return (unsigned short)r;
}
__device__ inline float b2f(unsigned short b) {
    return __uint_as_float(((unsigned)b) << 16);
}
__device__ inline unsigned pk2(float x, float y) {
    return (unsigned)f2b(x) | ((unsigned)f2b(y) << 16);
}
// packed bf16 atomic add (gfx940+ GLOBAL_ATOMIC_PK_ADD_BF16); no return needed
__device__ inline void atomic_pk(unsigned short* p, unsigned v) {
    asm volatile("global_atomic_pk_add_bf16 %0, %1, off"
                 :: "v"(p), "v"(v) : "memory");
}

// ---------------- fused conversion: x and ef -> bf16 (+ zero of invg|rd|hist) --

__global__ void conv_all(const float* __restrict__ x, unsigned short* __restrict__ xb, long n8x,
                         const float* __restrict__ ef, unsigned short* __restrict__ efB, long n8e,
                         unsigned* __restrict__ zb, long nz) {
    long i = (long)blockIdx.x * blockDim.x + threadIdx.x;
    const float* s;
    unsigned short* d;
    long idx;
    if (i < n8x) { s = x; d = xb; idx = i; }
    else if (i < n8x + n8e) { s = ef; d = efB; idx = i - n8x; }
    else if (i < n8x + n8e + nz) { zb[i - n8x - n8e] = 0u; return; }
    else return;
    float4 a = ((const float4*)s)[2 * idx];
    float4 b = ((const float4*)s)[2 * idx + 1];
    unsigned short o[8] = {f2b(a.x), f2b(a.y), f2b(a.z), f2b(a.w),
                           f2b(b.x), f2b(b.y), f2b(b.z), f2b(b.w)};
    ((uint4*)d)[idx] = *(uint4*)o;
}

// ---------------- fused weight transpose: 12 matrices in one launch ----------------

struct TpD { const float* W; unsigned short* WT; int K, F, Kp, rowOff; };
struct TpTab { TpD d[12]; };

__global__ void tp_all(TpTab t) {
    TpD dd = t.d[blockIdx.y];
    int f = blockIdx.x;
    if (f >= dd.F) return;
    for (int k = threadIdx.x; k < dd.Kp; k += blockDim.x)
        dd.WT[(size_t)f * dd.Kp + k] =
            (k < dd.K) ? f2b(dd.W[(size_t)(dd.rowOff + k) * dd.F + f]) : (unsigned short)0;
}

// ---------------- sort pipeline (R12: rank-memoized counting sort) ----------------

__global__ void hist_cnt(const int* __restrict__ dst, int* __restrict__ hist,
                         int* __restrict__ rankA,
                         const int* __restrict__ gid, float* __restrict__ gcnt) {
    int b = blockIdx.x;
    if (b < EB) {
        int e = b * 256 + threadIdx.x;
        if (e < EE) rankA[e] = atomicAdd(&hist[dst[e]], 1);
    } else {
        int n = (b - EB) * 256 + threadIdx.x;
        int l = threadIdx.x & 63;
        bool valid = n < NN;
        int g = valid ? gid[n] : -1;
        float v = valid ? 1.0f : 0.f;
        #pragma unroll
        for (int off = 1; off < 64; off <<= 1) {
            float vo = __shfl_up(v, off);
            int go = __shfl_up(g, off);
            if (l >= off && go == g) v += vo;
        }
        int gn = __shfl_down(g, 1);
        bool tail = (l == 63) || (gn != g);
        if (valid && tail) atomicAdd(&gcnt[g], v);
    }
}

// 3-phase exclusive scan of hist -> cursor
__global__ void scanA(const int* __restrict__ hist, int* __restrict__ bsum) {
    __shared__ int sb[256];
    int idx = blockIdx.x * 256 + threadIdx.x;
    sb[threadIdx.x] = (idx < NN) ? hist[idx] : 0;
    __syncthreads();
    for (int off = 128; off > 0; off >>= 1) {
        if (threadIdx.x < off) sb[threadIdx.x] += sb[threadIdx.x + off];
        __syncthreads();
    }
    if (threadIdx.x == 0) bsum[blockIdx.x] = sb[0];
}

__global__ void scanB(const int* __restrict__ bsum, int* __restrict__ boff) {
    __shared__ int sb[256];
    int t = threadIdx.x;
    int v = (t < SCB) ? bsum[t] : 0;
    sb[t] = v;
    __syncthreads();
    for (int off = 1; off < 256; off <<= 1) {
        int u = (t >= off) ? sb[t - off] : 0;
        __syncthreads();
        sb[t] += u;
        __syncthreads();
    }
    if (t < SCB) boff[t] = sb[t] - v;
}

// scanC + finalize_init fused: cursor(base), invdeg, invg, score-bias init
__global__ void scanC(const int* __restrict__ hist, const int* __restrict__ boff,
                      int* __restrict__ cursor, float* __restrict__ invdeg,
                      float* __restrict__ gcnt, float* __restrict__ score,
                      const float* __restrict__ bc0, const float* __restrict__ bc1,
                      const float* __restrict__ bc2, const float* __restrict__ bc3) {
    __shared__ int sb[256];
    int t = threadIdx.x;
    int idx = blockIdx.x * 256 + t;
    int v = (idx < NN) ? hist[idx] : 0;
    sb[t] = v;
    __syncthreads();
    for (int off = 1; off < 256; off <<= 1) {
        int u = (t >= off) ? sb[t - off] : 0;
        __syncthreads();
        sb[t] += u;
        __syncthreads();
    }
    if (idx < NN) {
        cursor[idx] = boff[blockIdx.x] + sb[t] - v;
        invdeg[idx] = 1.0f / fmaxf((float)v, 1.0f);
    }
    if (idx < GG) {
        float c = gcnt[idx];
        gcnt[idx] = 1.0f / fmaxf(c, 1.0f);
        score[idx] = (c > 0.0f) ? (bc0[0] + bc1[0] + bc2[0] + bc3[0]) : 0.0f;
    }
}

// scatter + ef gather fused — ATOMIC-FREE (R12): p = cursor-base + memoized rank
__global__ void scatter_kernel(const int* __restrict__ src, const int* __restrict__ dst,
                               const int* __restrict__ cursor, const int* __restrict__ rankA,
                               const unsigned short* __restrict__ efB,
                               int* __restrict__ srcS, int* __restrict__ dstS,
                               unsigned short* __restrict__ efS) {
    int e = blockIdx.x * blockDim.x + threadIdx.x;
    if (e < EE) {
        int d = dst[e];
        int p = cursor[d] + rankA[e];
        srcS[p] = src[e];
        dstS[p] = d;
        const uint4* s = (const uint4*)&efB[(size_t)e * 16];
        uint4* dd = (uint4*)&efS[(size_t)p * 16];
        dd[0] = s[0];
        dd[1] = s[1];
    }
}

// ---------------- nodeP: P = feat @ WmX  (+ fused bf16 agg-tile zeroing) ------

template<int FIN, int F, int CB>
__global__ __launch_bounds__(256)
void nodeP(const unsigned short* __restrict__ featB, const unsigned short* __restrict__ WxT,
           unsigned short* __restrict__ P, unsigned short* __restrict__ agg)
{
    constexpr int NT = CB / 16;
    const int tid = threadIdx.x;
    const int w   = tid >> 6;
    const int l   = tid & 63;
    const int l16 = l & 15;
    const int q   = l >> 4;
    const int cb  = blockIdx.y * CB;
    const int nb  = blockIdx.x * 64;
    const int row = nb + w * 16 + l16;

    // fused zeroing of this block's 64 x CB bf16 agg tile
    {
        const int zr = nb + (tid >> 2);
        const int zc = cb + (tid & 3) * (CB / 4);
        if (zr < NN) {
            const uint4 z4 = {0u, 0u, 0u, 0u};
            #pragma unroll
            for (int i = 0; i < CB / 32; ++i)
                ((uint4*)&agg[(size_t)zr * F + zc])[i] = z4;
        }
    }

    floatx4 acc[NT];
    #pragma unroll
    for (int nt = 0; nt < NT; ++nt) acc[nt] = (floatx4){0.f, 0.f, 0.f, 0.f};

    #pragma unroll
    for (int kb = 0; kb < FIN; kb += 32) {
        bf16x8 a = *(const bf16x8*)&featB[(size_t)row * FIN + kb + q * 8];
        #pragma unroll
        for (int nt = 0; nt < NT; ++nt) {
            bf16x8 b = *(const bf16x8*)&WxT[(size_t)(cb + nt * 16 + l16) * FIN + kb + q * 8];
            acc[nt] = __builtin_amdgcn_mfma_f32_16x16x32_bf16(a, b, acc[nt], 0, 0, 0);
        }
    }

    #pragma unroll
    for (int nt = 0; nt < NT; ++nt)
        #pragma unroll
        for (int r = 0; r < 4; ++r) {
            int ro = nb + w * 16 + q * 4 + r;
            P[(size_t)ro * F + cb + nt * 16 + l16] = f2b(acc[nt][r]);
        }
}

// ---------------- edge kernel: relu(efS@WmE + P[src] + bm)
// -> per-wave segmented reduce over sorted dst. CW=128 (2 cols/lane) or 64.
// R13: __launch_bounds__(128, 4) raises the VGPR cap 64->128 (R12 evidence:
// RA pinned 64 VGPR and serialized the 16 ds_reads + gathers per tile -> each
// row exposed ~120cy LDS latency; F=256's 2x-gather kernel NOT being slower
// disproved the bandwidth-ceiling theory). qv reads explicitly batched into a
// register array per tile so all 16 ds_reads issue back-to-back before the
// reduce arithmetic. Bit-identical semantics. LDS 16KB/block still gives 5
// waves/SIMD >= the declared 4. NO barriers (wave-private LDS). --------------

#define RXO(r) ((((r) >> 2 & 1) << 4) | (((r) >> 3 & 1) << 3))

template<int F>
__global__ __launch_bounds__(128, 4)
void edge_q(const unsigned short* __restrict__ efS,
            const int* __restrict__ srcS, const int* __restrict__ dstS,
            const unsigned short* __restrict__ WeT, const unsigned short* __restrict__ P,
            const float* __restrict__ bm, unsigned short* __restrict__ agg)
{
    constexpr int CW  = (F >= 128) ? 128 : 64;  // cols per wave
    constexpr int WPG = F / CW;                 // waves per 64-edge subtile (1 or 2)
    constexpr int NT  = CW / 16;
    constexpr int EPB = 64 * (2 / WPG);         // edges per block (128 or 64)
    constexpr int RS  = CW;                     // no pad; XOR swizzle instead

    __shared__ __align__(16) float red[2][16 * RS];

    const int tid = threadIdx.x;
    const int w   = tid >> 6;
    const int l   = tid & 63;
    const int l16 = l & 15;
    const int q   = l >> 4;
    const int sub = w / WPG;
    const int cb  = (w % WPG) * CW;
    const int be  = blockIdx.x * EPB + sub * 64;

    const int dreg = dstS[be + l];
    const int sreg = srcS[be + l];

    // end-of-segment mask (bit 63 always set); shfl MUST be unconditional (R6 bug)
    const int dnext = __shfl_down(dreg, 1);
    const unsigned long long em = __ballot((l == 63) || (dreg != dnext));

    const bf16x8 ZV = {0, 0, 0, 0, 0, 0, 0, 0};
    const int xo = ((q & 1) << 4) | ((q >> 1) << 3);  // phase-aware red swizzle
    float* redw = &red[w][0];

    // B fragments: WmE^T [F][32] (rows 16..31 zero-padded); bm as MFMA C-init
    bf16x8 bfr[NT];
    float  bmc[NT];
    #pragma unroll
    for (int nt = 0; nt < NT; ++nt) {
        bfr[nt] = *(const bf16x8*)&WeT[(size_t)(cb + nt * 16 + l16) * 32 + q * 8];
        bmc[nt] = bm[cb + nt * 16 + l16];
    }

    if constexpr (CW == 128) {
        float2 csum = {0.f, 0.f};
        bool first = true;

        #pragma unroll
        for (int mt = 0; mt < 4; ++mt) {
            bf16x8 a = ZV;
            if (q < 2) a = *(const bf16x8*)&efS[(size_t)(be + mt * 16 + l16) * 16 + q * 8];
            unsigned pvv[16];
            #pragma unroll
            for (int r = 0; r < 16; ++r) {
                int sr = __shfl(sreg, mt * 16 + r);
                pvv[r] = *(const unsigned*)&P[(size_t)sr * F + cb + 2 * l];
            }

            #pragma unroll
            for (int nt = 0; nt < NT; ++nt) {
                floatx4 acc = __builtin_amdgcn_mfma_f32_16x16x32_bf16(
                    a, bfr[nt], (floatx4){bmc[nt], bmc[nt], bmc[nt], bmc[nt]}, 0, 0, 0);
                #pragma unroll
                for (int r4 = 0; r4 < 4; ++r4)
                    redw[(q * 4 + r4) * RS + ((nt * 16 + l16) ^ xo)] = acc[r4];
            }

            // batch all 16 transpose reads before the reduce (hide LDS latency once)
            float2 qvv[16];
            #pragma unroll
            for (int r = 0; r < 16; ++r)
                qvv[r] = *(const float2*)&redw[r * RS + ((2 * l) ^ RXO(r))];

            #pragma unroll
            for (int r = 0; r < 16; ++r) {
                const int gr = mt * 16 + r;
                csum.x += fmaxf(qvv[r].x + __uint_as_float(pvv[r] << 16), 0.f);
                csum.y += fmaxf(qvv[r].y + __uint_as_float(pvv[r] & 0xffff0000u), 0.f);
                if ((em >> gr) & 1ull) {
                    int d = __shfl(dreg, gr);
                    unsigned short* ap = &agg[(size_t)d * F + cb + 2 * l];
                    unsigned pv = pk2(csum.x, csum.y);
                    if (first || gr == 63) atomic_pk(ap, pv);
                    else                   *(unsigned*)ap = pv;
                    csum.x = 0.f; csum.y = 0.f;
                    first = false;
                }
            }
        }
    } else {
        float csum = 0.f;
        bool first = true;

        #pragma unroll
        for (int mt = 0; mt < 4; ++mt) {
            bf16x8 a = ZV;
            if (q < 2) a = *(const bf16x8*)&efS[(size_t)(be + mt * 16 + l16) * 16 + q * 8];
            float pvv[16];
            #pragma unroll
            for (int r = 0; r < 16; ++r) {
                int sr = __shfl(sreg, mt * 16 + r);
                pvv[r] = b2f(P[(size_t)sr * F + cb + l]);
            }

            #pragma unroll
            for (int nt = 0; nt < NT; ++nt) {
                floatx4 acc = __builtin_amdgcn_mfma_f32_16x16x32_bf16(
                    a, bfr[nt], (floatx4){bmc[nt], bmc[nt], bmc[nt], bmc[nt]}, 0, 0, 0);
                #pragma unroll
                for (int r4 = 0; r4 < 4; ++r4)
                    redw[(q * 4 + r4) * RS + ((nt * 16 + l16) ^ xo)] = acc[r4];
            }

            float qvv[16];
            #pragma unroll
            for (int r = 0; r < 16; ++r)
                qvv[r] = redw[r * RS + (l ^ RXO(r))];

            #pragma unroll
            for (int r = 0; r < 16; ++r) {
                const int gr = mt * 16 + r;
                csum += fmaxf(qvv[r] + pvv[r], 0.f);
                if ((em >> gr) & 1ull) {
                    int d = __shfl(dreg, gr);
                    float cn = __shfl_down(csum, 1);   // uniform branch: all lanes execute
                    if ((l & 1) == 0) {
                        unsigned short* ap = &agg[(size_t)d * F + cb + l];
                        unsigned pv = pk2(csum, cn);
                        if (first || gr == 63) atomic_pk(ap, pv);
                        else                   *(unsigned*)ap = pv;
                    }
                    csum = 0.f;
                    first = false;
                }
            }
        }
    }
}

// ---------------- node MFMA GEMM: feat' = relu(agg*invdeg + feat@Ws + bs);
// per-node classifier dot accumulated into rd[n]. agg bf16. CB=64. ------------

template<int FIN, int F, int CB>
__global__ __launch_bounds__(256)
void node_mfma(const unsigned short* __restrict__ featB, const unsigned short* __restrict__ agg,
               const unsigned short* __restrict__ WsT, const float* __restrict__ bs,
               const float* __restrict__ Wc, const float* __restrict__ invdeg,
               unsigned short* __restrict__ fout, float* __restrict__ rd)
{
    constexpr int NT = CB / 16;
    const int tid = threadIdx.x;
    const int w   = tid >> 6;
    const int l   = tid & 63;
    const int l16 = l & 15;
    const int q   = l >> 4;
    const int cb  = blockIdx.y * CB;
    const int nb  = blockIdx.x * 64;
    const int row = nb + w * 16 + l16;

    floatx4 acc[NT];
    #pragma unroll
    for (int nt = 0; nt < NT; ++nt) acc[nt] = (floatx4){0.f, 0.f, 0.f, 0.f};

    #pragma unroll
    for (int kb = 0; kb < FIN; kb += 32) {
        bf16x8 a = *(const bf16x8*)&featB[(size_t)row * FIN + kb + q * 8];
        #pragma unroll
        for (int nt = 0; nt < NT; ++nt) {
            bf16x8 b = *(const bf16x8*)&WsT[(size_t)(cb + nt * 16 + l16) * FIN + kb + q * 8];
            acc[nt] = __builtin_amdgcn_mfma_f32_16x16x32_bf16(a, b, acc[nt], 0, 0, 0);
        }
    }

    float wcv[NT], bsv[NT];
    #pragma unroll
    for (int nt = 0; nt < NT; ++nt) {
        wcv[nt] = Wc[cb + nt * 16 + l16];
        bsv[nt] = bs[cb + nt * 16 + l16];
    }

    #pragma unroll
    for (int r = 0; r < 4; ++r) {
        int n = nb + w * 16 + q * 4 + r;
        bool valid = n < NN;
        float idg = valid ? invdeg[n] : 0.f;
        float s = 0.f;
        #pragma unroll
        for (int nt = 0; nt < NT; ++nt) {
            int col = cb + nt * 16 + l16;
            float av = valid ? b2f(agg[(size_t)n * F + col]) : 0.f;
            float v = fmaxf(acc[nt][r] + av * idg + bsv[nt], 0.f);
            if (valid) fout[(size_t)n * F + col] = f2b(v);
            s += v * wcv[nt];
        }
        s += __shfl_xor(s, 1);
        s += __shfl_xor(s, 2);
        s += __shfl_xor(s, 4);
        s += __shfl_xor(s, 8);
        if (valid && l16 == 0) atomicAdd(&rd[n], s);
    }
}

// ---------------- final: score[g] += invg[g] * segmented-sum(rd) over sorted gid ----------------

__global__ void score_reduce(const float* __restrict__ rd, const int* __restrict__ gid,
                             const float* __restrict__ invg, float* __restrict__ score) {
    int n = blockIdx.x * blockDim.x + threadIdx.x;
    int l = threadIdx.x & 63;
    bool valid = n < NN;
    int g = valid ? gid[n] : -1;
    float v = valid ? rd[n] : 0.f;
    #pragma unroll
    for (int off = 1; off < 64; off <<= 1) {
        float vo = __shfl_up(v, off);
        int go = __shfl_up(g, off);
        if (l >= off && go == g) v += vo;
    }
    int gn = __shfl_down(g, 1);
    bool tail = (l == 63) || (gn != g);
    if (valid && tail) atomicAdd(&score[g], v * invg[g]);
}

// ---------------- host ----------------

extern "C" void kernel_launch(void* const* d_in, const int* in_sizes, int n_in,
                              void* d_out, int out_size, void* d_ws, size_t ws_size,
                              hipStream_t stream) {
    const float* x   = (const float*)d_in[0];
    const float* ef  = (const float*)d_in[1];
    const int*   src = (const int*)d_in[2];
    const int*   dst = (const int*)d_in[3];
    const int*   gid = (const int*)d_in[4];
    const float *Wm[4], *bm[4], *Ws[4], *bs[4], *Wc[4], *bc[4];
    for (int i = 0; i < 4; ++i) {
        Wm[i] = (const float*)d_in[5 + 6 * i];
        bm[i] = (const float*)d_in[6 + 6 * i];
        Ws[i] = (const float*)d_in[7 + 6 * i];
        bs[i] = (const float*)d_in[8 + 6 * i];
        Wc[i] = (const float*)d_in[9 + 6 * i];
        bc[i] = (const float*)d_in[10 + 6 * i];
    }

    char* w = (char*)d_ws;
    unsigned short* agg = (unsigned short*)w;  w += (size_t)NN * 256 * 4;  // bf16 (region kept fp32-sized)
    unsigned short* xb  = (unsigned short*)w; w += (size_t)NP * 32 * 2;
    unsigned short* f1  = (unsigned short*)w; w += (size_t)NP * 64 * 2;
    unsigned short* f2  = (unsigned short*)w; w += (size_t)NP * 128 * 2;
    unsigned short* f3  = (unsigned short*)w; w += (size_t)NP * 128 * 2;
    unsigned short* f4  = (unsigned short*)w; w += (size_t)NP * 256 * 2;
    unsigned short* P   = (unsigned short*)w; w += (size_t)NP * 256 * 2;
    unsigned short* efB = (unsigned short*)w; w += (size_t)EE * 16 * 2;
    unsigned short* efS = (unsigned short*)w; w += (size_t)EE * 16 * 2;
    unsigned short* WxT0 = (unsigned short*)w; w += (size_t)64 * 32 * 2;
    unsigned short* WxT1 = (unsigned short*)w; w += (size_t)128 * 64 * 2;
    unsigned short* WxT2 = (unsigned short*)w; w += (size_t)128 * 128 * 2;
    unsigned short* WxT3 = (unsigned short*)w; w += (size_t)256 * 128 * 2;
    unsigned short* WeT0 = (unsigned short*)w; w += (size_t)64 * 32 * 2;
    unsigned short* WeT1 = (unsigned short*)w; w += (size_t)128 * 32 * 2;
    unsigned short* WeT2 = (unsigned short*)w; w += (size_t)128 * 32 * 2;
    unsigned short* WeT3 = (unsigned short*)w; w += (size_t)256 * 32 * 2;
    unsigned short* WsT0 = (unsigned short*)w; w += (size_t)64 * 32 * 2;
    unsigned short* WsT1 = (unsigned short*)w; w += (size_t)128 * 64 * 2;
    unsigned short* WsT2 = (unsigned short*)w; w += (size_t)128 * 128 * 2;
    unsigned short* WsT3 = (unsigned short*)w; w += (size_t)256 * 128 * 2;
    float* invdeg = (float*)w;               w += (size_t)NN * 4;
    // contiguous zero-block: invg | rd | hist  (zeroed inside conv_all)
    float* invg   = (float*)w;               w += (size_t)GG * 4;
    float* rd     = (float*)w;               w += (size_t)NN * 4;
    int* hist   = (int*)w;                   w += (size_t)(NN + 1) * 4;
    int* srcS   = (int*)w;                   w += (size_t)EE * 4;
    int* dstS   = (int*)w;                   w += (size_t)EE * 4;
    int* bsum   = (int*)w;                   w += (size_t)SCB * 4;
    int* boff   = (int*)w;                   w += (size_t)SCB * 4;
    int* cursor = (int*)w;                   w += (size_t)NN * 4;
    float* score = (float*)d_out;

    // rank[] aliases the agg region (dead until layer-0 nodeP overwrites it;
    // scatter — the last reader — precedes nodeP0 in stream order)
    int* rankA = (int*)agg;

    // ---- conversions / weight prep / zero-init (fused launches) ----
    const long n8x = (long)NN * 32 / 8, n8e = (long)EE * 16 / 8;
    const long nz  = GG + NN + NN + 1;   // invg | rd | hist words
    conv_all<<<(n8x + n8e + nz + 255) / 256, 256, 0, stream>>>(
        x, xb, n8x, ef, efB, n8e, (unsigned*)invg, nz);

    TpTab tt;
    tt.d[0]  = {Wm[0], WxT0,  32,  64,  32,   0};
    tt.d[1]  = {Wm[1], WxT1,  64, 128,  64,   0};
    tt.d[2]  = {Wm[2], WxT2, 128, 128, 128,   0};
    tt.d[3]  = {Wm[3], WxT3, 128, 256, 128,   0};
    tt.d[4]  = {Wm[0], WeT0,  16,  64,  32,  32};
    tt.d[5]  = {Wm[1], WeT1,  16, 128,  32,  64};
    tt.d[6]  = {Wm[2], WeT2,  16, 128,  32, 128};
    tt.d[7]  = {Wm[3], WeT3,  16, 256,  32, 128};
    tt.d[8]  = {Ws[0], WsT0,  32,  64,  32,   0};
    tt.d[9]  = {Ws[1], WsT1,  64, 128,  64,   0};
    tt.d[10] = {Ws[2], WsT2, 128, 128, 128,   0};
    tt.d[11] = {Ws[3], WsT3, 128, 256, 128,   0};
    tp_all<<<dim3(256, 12), 256, 0, stream>>>(tt);

    // ---- sort edges by dst (rank-memoized counting sort) ----
    hist_cnt<<<EB + SCB, 256, 0, stream>>>(dst, hist, rankA, gid, invg);
    scanA<<<SCB, 256, 0, stream>>>(hist, bsum);
    scanB<<<1, 256, 0, stream>>>(bsum, boff);
    scanC<<<SCB, 256, 0, stream>>>(hist, boff, cursor, invdeg, invg, score,
                                   bc[0], bc[1], bc[2], bc[3]);
    scatter_kernel<<<EB, 256, 0, stream>>>(src, dst, cursor, rankA, efB, srcS, dstS, efS);

    const int NB = NP / 64;            // 782

    // layer 0: fin=32, f=64  (CW=64, 2-wave blocks EPB=128; CB=64)
    nodeP<32, 64, 64><<<dim3(NB, 1), 256, 0, stream>>>(xb, WxT0, P, agg);
    edge_q<64><<<EE / 128, 128, 0, stream>>>(efS, srcS, dstS, WeT0, P, bm[0], agg);
    node_mfma<32, 64, 64><<<dim3(NB, 1), 256, 0, stream>>>(xb, agg, WsT0, bs[0], Wc[0], invdeg, f1, rd);

    // layer 1: fin=64, f=128  (CW=128, EPB=128; CB=64)
    nodeP<64, 128, 64><<<dim3(NB, 2), 256, 0, stream>>>(f1, WxT1, P, agg);
    edge_q<128><<<EE / 128, 128, 0, stream>>>(efS, srcS, dstS, WeT1, P, bm[1], agg);
    node_mfma<64, 128, 64><<<dim3(NB, 2), 256, 0, stream>>>(f1, agg, WsT1, bs[1], Wc[1], invdeg, f2, rd);

    // layer 2: fin=128, f=128  (CW=128, EPB=128; CB=64)
    nodeP<128, 128, 64><<<dim3(NB, 2), 256, 0, stream>>>(f2, WxT2, P, agg);
    edge_q<128><<<EE / 128, 128, 0, stream>>>(efS, srcS, dstS, WeT2, P, bm[2], agg);
    node_mfma<128, 128, 64><<<dim3(NB, 2), 256, 0, stream>>>(f2, agg, WsT2, bs[2], Wc[2], invdeg, f3, rd);

    // layer 3: fin=128, f=256  (CW=128, WPG=2, EPB=64; CB=64)
    nodeP<128, 256, 64><<<dim3(NB, 4), 256, 0, stream>>>(f3, WxT3, P, agg);
    edge_q<256><<<EE / 64, 128, 0, stream>>>(efS, srcS, dstS, WeT3, P, bm[3], agg);
    node_mfma<128, 256, 64><<<dim3(NB, 4), 256, 0, stream>>>(f3, agg, WsT3, bs[3], Wc[3], invdeg, f4, rd);

    // final per-graph mean of accumulated classifier dots
    score_reduce<<<SCB, 256, 0, stream>>>(rd, gid, invg, score);
}

// Round 14
// 587.066 us; speedup vs baseline: 1.0989x; 1.0989x over previous
//
#include <hip/hip_runtime.h>

#define NN 50000
#define EE 800000
#define GG 512
#define NP 50048   // NN padded to multiple of 64
#define EB 3125    // edge blocks of 256
#define SCB 196    // scan blocks of 256 covering NN

typedef short bf16x8 __attribute__((ext_vector_type(8)));
typedef float floatx4 __attribute__((ext_vector_type(4)));

__device__ inline unsigned short f2b(float f) {
    unsigned u = __float_as_uint(f);
    unsigned r = (u + 0x7fffu + ((u >> 16) & 1u)) >> 16;
    return (unsigned short)r;
}
__device__ inline float b2f(unsigned short b) {
    return __uint_as_float(((unsigned)b) << 16);
}
__device__ inline unsigned pk2(float x, float y) {
    return (unsigned)f2b(x) | ((unsigned)f2b(y) << 16);
}
// packed bf16 atomic add (gfx940+ GLOBAL_ATOMIC_PK_ADD_BF16); no return needed
__device__ inline void atomic_pk(unsigned short* p, unsigned v) {
    asm volatile("global_atomic_pk_add_bf16 %0, %1, off"
                 :: "v"(p), "v"(v) : "memory");
}

// ---------------- fused conversion: x and ef -> bf16 (+ zero of invg|rd|hist) --

__global__ void conv_all(const float* __restrict__ x, unsigned short* __restrict__ xb, long n8x,
                         const float* __restrict__ ef, unsigned short* __restrict__ efB, long n8e,
                         unsigned* __restrict__ zb, long nz) {
    long i = (long)blockIdx.x * blockDim.x + threadIdx.x;
    const float* s;
    unsigned short* d;
    long idx;
    if (i < n8x) { s = x; d = xb; idx = i; }
    else if (i < n8x + n8e) { s = ef; d = efB; idx = i - n8x; }
    else if (i < n8x + n8e + nz) { zb[i - n8x - n8e] = 0u; return; }
    else return;
    float4 a = ((const float4*)s)[2 * idx];
    float4 b = ((const float4*)s)[2 * idx + 1];
    unsigned short o[8] = {f2b(a.x), f2b(a.y), f2b(a.z), f2b(a.w),
                           f2b(b.x), f2b(b.y), f2b(b.z), f2b(b.w)};
    ((uint4*)d)[idx] = *(uint4*)o;
}

// ---------------- fused weight transpose: 12 matrices in one launch ----------------

struct TpD { const float* W; unsigned short* WT; int K, F, Kp, rowOff; };
struct TpTab { TpD d[12]; };

__global__ void tp_all(TpTab t) {
    TpD dd = t.d[blockIdx.y];
    int f = blockIdx.x;
    if (f >= dd.F) return;
    for (int k = threadIdx.x; k < dd.Kp; k += blockDim.x)
        dd.WT[(size_t)f * dd.Kp + k] =
            (k < dd.K) ? f2b(dd.W[(size_t)(dd.rowOff + k) * dd.F + f]) : (unsigned short)0;
}

// ---------------- sort pipeline (R12: rank-memoized counting sort) ----------------

__global__ void hist_cnt(const int* __restrict__ dst, int* __restrict__ hist,
                         int* __restrict__ rankA,
                         const int* __restrict__ gid, float* __restrict__ gcnt) {
    int b = blockIdx.x;
    if (b < EB) {
        int e = b * 256 + threadIdx.x;
        if (e < EE) rankA[e] = atomicAdd(&hist[dst[e]], 1);
    } else {
        int n = (b - EB) * 256 + threadIdx.x;
        int l = threadIdx.x & 63;
        bool valid = n < NN;
        int g = valid ? gid[n] : -1;
        float v = valid ? 1.0f : 0.f;
        #pragma unroll
        for (int off = 1; off < 64; off <<= 1) {
            float vo = __shfl_up(v, off);
            int go = __shfl_up(g, off);
            if (l >= off && go == g) v += vo;
        }
        int gn = __shfl_down(g, 1);
        bool tail = (l == 63) || (gn != g);
        if (valid && tail) atomicAdd(&gcnt[g], v);
    }
}

// 3-phase exclusive scan of hist -> cursor
__global__ void scanA(const int* __restrict__ hist, int* __restrict__ bsum) {
    __shared__ int sb[256];
    int idx = blockIdx.x * 256 + threadIdx.x;
    sb[threadIdx.x] = (idx < NN) ? hist[idx] : 0;
    __syncthreads();
    for (int off = 128; off > 0; off >>= 1) {
        if (threadIdx.x < off) sb[threadIdx.x] += sb[threadIdx.x + off];
        __syncthreads();
    }
    if (threadIdx.x == 0) bsum[blockIdx.x] = sb[0];
}

__global__ void scanB(const int* __restrict__ bsum, int* __restrict__ boff) {
    __shared__ int sb[256];
    int t = threadIdx.x;
    int v = (t < SCB) ? bsum[t] : 0;
    sb[t] = v;
    __syncthreads();
    for (int off = 1; off < 256; off <<= 1) {
        int u = (t >= off) ? sb[t - off] : 0;
        __syncthreads();
        sb[t] += u;
        __syncthreads();
    }
    if (t < SCB) boff[t] = sb[t] - v;
}

// scanC + finalize_init fused: cursor(base), invdeg, invg, score-bias init
__global__ void scanC(const int* __restrict__ hist, const int* __restrict__ boff,
                      int* __restrict__ cursor, float* __restrict__ invdeg,
                      float* __restrict__ gcnt, float* __restrict__ score,
                      const float* __restrict__ bc0, const float* __restrict__ bc1,
                      const float* __restrict__ bc2, const float* __restrict__ bc3) {
    __shared__ int sb[256];
    int t = threadIdx.x;
    int idx = blockIdx.x * 256 + t;
    int v = (idx < NN) ? hist[idx] : 0;
    sb[t] = v;
    __syncthreads();
    for (int off = 1; off < 256; off <<= 1) {
        int u = (t >= off) ? sb[t - off] : 0;
        __syncthreads();
        sb[t] += u;
        __syncthreads();
    }
    if (idx < NN) {
        cursor[idx] = boff[blockIdx.x] + sb[t] - v;
        invdeg[idx] = 1.0f / fmaxf((float)v, 1.0f);
    }
    if (idx < GG) {
        float c = gcnt[idx];
        gcnt[idx] = 1.0f / fmaxf(c, 1.0f);
        score[idx] = (c > 0.0f) ? (bc0[0] + bc1[0] + bc2[0] + bc3[0]) : 0.0f;
    }
}

// scatter + ef gather fused — ATOMIC-FREE (R12): p = cursor-base + memoized rank
__global__ void scatter_kernel(const int* __restrict__ src, const int* __restrict__ dst,
                               const int* __restrict__ cursor, const int* __restrict__ rankA,
                               const unsigned short* __restrict__ efB,
                               int* __restrict__ srcS, int* __restrict__ dstS,
                               unsigned short* __restrict__ efS) {
    int e = blockIdx.x * blockDim.x + threadIdx.x;
    if (e < EE) {
        int d = dst[e];
        int p = cursor[d] + rankA[e];
        srcS[p] = src[e];
        dstS[p] = d;
        const uint4* s = (const uint4*)&efB[(size_t)e * 16];
        uint4* dd = (uint4*)&efS[(size_t)p * 16];
        dd[0] = s[0];
        dd[1] = s[1];
    }
}

// ---------------- nodeP: P = feat @ WmX  (+ fused bf16 agg-tile zeroing) ------

template<int FIN, int F, int CB>
__global__ __launch_bounds__(256)
void nodeP(const unsigned short* __restrict__ featB, const unsigned short* __restrict__ WxT,
           unsigned short* __restrict__ P, unsigned short* __restrict__ agg)
{
    constexpr int NT = CB / 16;
    const int tid = threadIdx.x;
    const int w   = tid >> 6;
    const int l   = tid & 63;
    const int l16 = l & 15;
    const int q   = l >> 4;
    const int cb  = blockIdx.y * CB;
    const int nb  = blockIdx.x * 64;
    const int row = nb + w * 16 + l16;

    // fused zeroing of this block's 64 x CB bf16 agg tile
    {
        const int zr = nb + (tid >> 2);
        const int zc = cb + (tid & 3) * (CB / 4);
        if (zr < NN) {
            const uint4 z4 = {0u, 0u, 0u, 0u};
            #pragma unroll
            for (int i = 0; i < CB / 32; ++i)
                ((uint4*)&agg[(size_t)zr * F + zc])[i] = z4;
        }
    }

    floatx4 acc[NT];
    #pragma unroll
    for (int nt = 0; nt < NT; ++nt) acc[nt] = (floatx4){0.f, 0.f, 0.f, 0.f};

    #pragma unroll
    for (int kb = 0; kb < FIN; kb += 32) {
        bf16x8 a = *(const bf16x8*)&featB[(size_t)row * FIN + kb + q * 8];
        #pragma unroll
        for (int nt = 0; nt < NT; ++nt) {
            bf16x8 b = *(const bf16x8*)&WxT[(size_t)(cb + nt * 16 + l16) * FIN + kb + q * 8];
            acc[nt] = __builtin_amdgcn_mfma_f32_16x16x32_bf16(a, b, acc[nt], 0, 0, 0);
        }
    }

    #pragma unroll
    for (int nt = 0; nt < NT; ++nt)
        #pragma unroll
        for (int r = 0; r < 4; ++r) {
            int ro = nb + w * 16 + q * 4 + r;
            P[(size_t)ro * F + cb + nt * 16 + l16] = f2b(acc[nt][r]);
        }
}

// ---------------- edge kernel: relu(efS@WmE + P[src] + bm)
// -> per-wave segmented reduce over sorted dst. CW=128 (2 cols/lane) or 64.
// R14 = R12 VERBATIM (589µs best; R13's batched-reads + (128,4) spilled —
// VGPR pinned 64, WRITE +75MB scratch, 5th RA-fight failure) + s_setprio(1)
// around the MFMA+LDS-write phase. SOPP hint: zero register cost, no numeric
// effect. Mechanism: barrier-free independent waves are naturally de-phased;
// priority lets compute-phase waves win issue arbitration over gather-issuing
// waves (documented +4-7% in the analogous attn regime). NO barriers. --------

#define RXO(r) ((((r) >> 2 & 1) << 4) | (((r) >> 3 & 1) << 3))

template<int F>
__global__ __launch_bounds__(128)
void edge_q(const unsigned short* __restrict__ efS,
            const int* __restrict__ srcS, const int* __restrict__ dstS,
            const unsigned short* __restrict__ WeT, const unsigned short* __restrict__ P,
            const float* __restrict__ bm, unsigned short* __restrict__ agg)
{
    constexpr int CW  = (F >= 128) ? 128 : 64;  // cols per wave
    constexpr int WPG = F / CW;                 // waves per 64-edge subtile (1 or 2)
    constexpr int NT  = CW / 16;
    constexpr int EPB = 64 * (2 / WPG);         // edges per block (128 or 64)
    constexpr int RS  = CW;                     // no pad; XOR swizzle instead

    __shared__ __align__(16) float red[2][16 * RS];

    const int tid = threadIdx.x;
    const int w   = tid >> 6;
    const int l   = tid & 63;
    const int l16 = l & 15;
    const int q   = l >> 4;
    const int sub = w / WPG;
    const int cb  = (w % WPG) * CW;
    const int be  = blockIdx.x * EPB + sub * 64;

    const int dreg = dstS[be + l];
    const int sreg = srcS[be + l];

    // end-of-segment mask (bit 63 always set); shfl MUST be unconditional (R6 bug)
    const int dnext = __shfl_down(dreg, 1);
    const unsigned long long em = __ballot((l == 63) || (dreg != dnext));

    const bf16x8 ZV = {0, 0, 0, 0, 0, 0, 0, 0};
    const int xo = ((q & 1) << 4) | ((q >> 1) << 3);  // phase-aware red swizzle
    float* redw = &red[w][0];

    // B fragments: WmE^T [F][32] (rows 16..31 zero-padded); bm as MFMA C-init
    bf16x8 bfr[NT];
    float  bmc[NT];
    #pragma unroll
    for (int nt = 0; nt < NT; ++nt) {
        bfr[nt] = *(const bf16x8*)&WeT[(size_t)(cb + nt * 16 + l16) * 32 + q * 8];
        bmc[nt] = bm[cb + nt * 16 + l16];
    }

    if constexpr (CW == 128) {
        float2 csum = {0.f, 0.f};
        bool first = true;

        #pragma unroll
        for (int mt = 0; mt < 4; ++mt) {
            bf16x8 a = ZV;
            if (q < 2) a = *(const bf16x8*)&efS[(size_t)(be + mt * 16 + l16) * 16 + q * 8];
            unsigned pvv[16];
            #pragma unroll
            for (int r = 0; r < 16; ++r) {
                int sr = __shfl(sreg, mt * 16 + r);
                pvv[r] = *(const unsigned*)&P[(size_t)sr * F + cb + 2 * l];
            }

            __builtin_amdgcn_s_setprio(1);
            #pragma unroll
            for (int nt = 0; nt < NT; ++nt) {
                floatx4 acc = __builtin_amdgcn_mfma_f32_16x16x32_bf16(
                    a, bfr[nt], (floatx4){bmc[nt], bmc[nt], bmc[nt], bmc[nt]}, 0, 0, 0);
                #pragma unroll
                for (int r4 = 0; r4 < 4; ++r4)
                    redw[(q * 4 + r4) * RS + ((nt * 16 + l16) ^ xo)] = acc[r4];
            }
            __builtin_amdgcn_s_setprio(0);

            #pragma unroll
            for (int r = 0; r < 16; ++r) {
                const int gr = mt * 16 + r;
                float2 qv = *(const float2*)&redw[r * RS + ((2 * l) ^ RXO(r))];
                csum.x += fmaxf(qv.x + __uint_as_float(pvv[r] << 16), 0.f);
                csum.y += fmaxf(qv.y + __uint_as_float(pvv[r] & 0xffff0000u), 0.f);
                if ((em >> gr) & 1ull) {
                    int d = __shfl(dreg, gr);
                    unsigned short* ap = &agg[(size_t)d * F + cb + 2 * l];
                    unsigned pv = pk2(csum.x, csum.y);
                    if (first || gr == 63) atomic_pk(ap, pv);
                    else                   *(unsigned*)ap = pv;
                    csum.x = 0.f; csum.y = 0.f;
                    first = false;
                }
            }
        }
    } else {
        float csum = 0.f;
        bool first = true;

        #pragma unroll
        for (int mt = 0; mt < 4; ++mt) {
            bf16x8 a = ZV;
            if (q < 2) a = *(const bf16x8*)&efS[(size_t)(be + mt * 16 + l16) * 16 + q * 8];
            float pvv[16];
            #pragma unroll
            for (int r = 0; r < 16; ++r) {
                int sr = __shfl(sreg, mt * 16 + r);
                pvv[r] = b2f(P[(size_t)sr * F + cb + l]);
            }

            __builtin_amdgcn_s_setprio(1);
            #pragma unroll
            for (int nt = 0; nt < NT; ++nt) {
                floatx4 acc = __builtin_amdgcn_mfma_f32_16x16x32_bf16(
                    a, bfr[nt], (floatx4){bmc[nt], bmc[nt], bmc[nt], bmc[nt]}, 0, 0, 0);
                #pragma unroll
                for (int r4 = 0; r4 < 4; ++r4)
                    redw[(q * 4 + r4) * RS + ((nt * 16 + l16) ^ xo)] = acc[r4];
            }
            __builtin_amdgcn_s_setprio(0);

            #pragma unroll
            for (int r = 0; r < 16; ++r) {
                const int gr = mt * 16 + r;
                float qv = redw[r * RS + (l ^ RXO(r))];
                csum += fmaxf(qv + pvv[r], 0.f);
                if ((em >> gr) & 1ull) {
                    int d = __shfl(dreg, gr);
                    float cn = __shfl_down(csum, 1);   // uniform branch: all lanes execute
                    if ((l & 1) == 0) {
                        unsigned short* ap = &agg[(size_t)d * F + cb + l];
                        unsigned pv = pk2(csum, cn);
                        if (first || gr == 63) atomic_pk(ap, pv);
                        else                   *(unsigned*)ap = pv;
                    }
                    csum = 0.f;
                    first = false;
                }
            }
        }
    }
}

// ---------------- node MFMA GEMM: feat' = relu(agg*invdeg + feat@Ws + bs);
// per-node classifier dot accumulated into rd[n]. agg bf16. CB=64. ------------

template<int FIN, int F, int CB>
__global__ __launch_bounds__(256)
void node_mfma(const unsigned short* __restrict__ featB, const unsigned short* __restrict__ agg,
               const unsigned short* __restrict__ WsT, const float* __restrict__ bs,
               const float* __restrict__ Wc, const float* __restrict__ invdeg,
               unsigned short* __restrict__ fout, float* __restrict__ rd)
{
    constexpr int NT = CB / 16;
    const int tid = threadIdx.x;
    const int w   = tid >> 6;
    const int l   = tid & 63;
    const int l16 = l & 15;
    const int q   = l >> 4;
    const int cb  = blockIdx.y * CB;
    const int nb  = blockIdx.x * 64;
    const int row = nb + w * 16 + l16;

    floatx4 acc[NT];
    #pragma unroll
    for (int nt = 0; nt < NT; ++nt) acc[nt] = (floatx4){0.f, 0.f, 0.f, 0.f};

    #pragma unroll
    for (int kb = 0; kb < FIN; kb += 32) {
        bf16x8 a = *(const bf16x8*)&featB[(size_t)row * FIN + kb + q * 8];
        #pragma unroll
        for (int nt = 0; nt < NT; ++nt) {
            bf16x8 b = *(const bf16x8*)&WsT[(size_t)(cb + nt * 16 + l16) * FIN + kb + q * 8];
            acc[nt] = __builtin_amdgcn_mfma_f32_16x16x32_bf16(a, b, acc[nt], 0, 0, 0);
        }
    }

    float wcv[NT], bsv[NT];
    #pragma unroll
    for (int nt = 0; nt < NT; ++nt) {
        wcv[nt] = Wc[cb + nt * 16 + l16];
        bsv[nt] = bs[cb + nt * 16 + l16];
    }

    #pragma unroll
    for (int r = 0; r < 4; ++r) {
        int n = nb + w * 16 + q * 4 + r;
        bool valid = n < NN;
        float idg = valid ? invdeg[n] : 0.f;
        float s = 0.f;
        #pragma unroll
        for (int nt = 0; nt < NT; ++nt) {
            int col = cb + nt * 16 + l16;
            float av = valid ? b2f(agg[(size_t)n * F + col]) : 0.f;
            float v = fmaxf(acc[nt][r] + av * idg + bsv[nt], 0.f);
            if (valid) fout[(size_t)n * F + col] = f2b(v);
            s += v * wcv[nt];
        }
        s += __shfl_xor(s, 1);
        s += __shfl_xor(s, 2);
        s += __shfl_xor(s, 4);
        s += __shfl_xor(s, 8);
        if (valid && l16 == 0) atomicAdd(&rd[n], s);
    }
}

// ---------------- final: score[g] += invg[g] * segmented-sum(rd) over sorted gid ----------------

__global__ void score_reduce(const float* __restrict__ rd, const int* __restrict__ gid,
                             const float* __restrict__ invg, float* __restrict__ score) {
    int n = blockIdx.x * blockDim.x + threadIdx.x;
    int l = threadIdx.x & 63;
    bool valid = n < NN;
    int g = valid ? gid[n] : -1;
    float v = valid ? rd[n] : 0.f;
    #pragma unroll
    for (int off = 1; off < 64; off <<= 1) {
        float vo = __shfl_up(v, off);
        int go = __shfl_up(g, off);
        if (l >= off && go == g) v += vo;
    }
    int gn = __shfl_down(g, 1);
    bool tail = (l == 63) || (gn != g);
    if (valid && tail) atomicAdd(&score[g], v * invg[g]);
}

// ---------------- host ----------------

extern "C" void kernel_launch(void* const* d_in, const int* in_sizes, int n_in,
                              void* d_out, int out_size, void* d_ws, size_t ws_size,
                              hipStream_t stream) {
    const float* x   = (const float*)d_in[0];
    const float* ef  = (const float*)d_in[1];
    const int*   src = (const int*)d_in[2];
    const int*   dst = (const int*)d_in[3];
    const int*   gid = (const int*)d_in[4];
    const float *Wm[4], *bm[4], *Ws[4], *bs[4], *Wc[4], *bc[4];
    for (int i = 0; i < 4; ++i) {
        Wm[i] = (const float*)d_in[5 + 6 * i];
        bm[i] = (const float*)d_in[6 + 6 * i];
        Ws[i] = (const float*)d_in[7 + 6 * i];
        bs[i] = (const float*)d_in[8 + 6 * i];
        Wc[i] = (const float*)d_in[9 + 6 * i];
        bc[i] = (const float*)d_in[10 + 6 * i];
    }

    char* w = (char*)d_ws;
    unsigned short* agg = (unsigned short*)w;  w += (size_t)NN * 256 * 4;  // bf16 (region kept fp32-sized)
    unsigned short* xb  = (unsigned short*)w; w += (size_t)NP * 32 * 2;
    unsigned short* f1  = (unsigned short*)w; w += (size_t)NP * 64 * 2;
    unsigned short* f2  = (unsigned short*)w; w += (size_t)NP * 128 * 2;
    unsigned short* f3  = (unsigned short*)w; w += (size_t)NP * 128 * 2;
    unsigned short* f4  = (unsigned short*)w; w += (size_t)NP * 256 * 2;
    unsigned short* P   = (unsigned short*)w; w += (size_t)NP * 256 * 2;
    unsigned short* efB = (unsigned short*)w; w += (size_t)EE * 16 * 2;
    unsigned short* efS = (unsigned short*)w; w += (size_t)EE * 16 * 2;
    unsigned short* WxT0 = (unsigned short*)w; w += (size_t)64 * 32 * 2;
    unsigned short* WxT1 = (unsigned short*)w; w += (size_t)128 * 64 * 2;
    unsigned short* WxT2 = (unsigned short*)w; w += (size_t)128 * 128 * 2;
    unsigned short* WxT3 = (unsigned short*)w; w += (size_t)256 * 128 * 2;
    unsigned short* WeT0 = (unsigned short*)w; w += (size_t)64 * 32 * 2;
    unsigned short* WeT1 = (unsigned short*)w; w += (size_t)128 * 32 * 2;
    unsigned short* WeT2 = (unsigned short*)w; w += (size_t)128 * 32 * 2;
    unsigned short* WeT3 = (unsigned short*)w; w += (size_t)256 * 32 * 2;
    unsigned short* WsT0 = (unsigned short*)w; w += (size_t)64 * 32 * 2;
    unsigned short* WsT1 = (unsigned short*)w; w += (size_t)128 * 64 * 2;
    unsigned short* WsT2 = (unsigned short*)w; w += (size_t)128 * 128 * 2;
    unsigned short* WsT3 = (unsigned short*)w; w += (size_t)256 * 128 * 2;
    float* invdeg = (float*)w;               w += (size_t)NN * 4;
    // contiguous zero-block: invg | rd | hist  (zeroed inside conv_all)
    float* invg   = (float*)w;               w += (size_t)GG * 4;
    float* rd     = (float*)w;               w += (size_t)NN * 4;
    int* hist   = (int*)w;                   w += (size_t)(NN + 1) * 4;
    int* srcS   = (int*)w;                   w += (size_t)EE * 4;
    int* dstS   = (int*)w;                   w += (size_t)EE * 4;
    int* bsum   = (int*)w;                   w += (size_t)SCB * 4;
    int* boff   = (int*)w;                   w += (size_t)SCB * 4;
    int* cursor = (int*)w;                   w += (size_t)NN * 4;
    float* score = (float*)d_out;

    // rank[] aliases the agg region (dead until layer-0 nodeP overwrites it;
    // scatter — the last reader — precedes nodeP0 in stream order)
    int* rankA = (int*)agg;

    // ---- conversions / weight prep / zero-init (fused launches) ----
    const long n8x = (long)NN * 32 / 8, n8e = (long)EE * 16 / 8;
    const long nz  = GG + NN + NN + 1;   // invg | rd | hist words
    conv_all<<<(n8x + n8e + nz + 255) / 256, 256, 0, stream>>>(
        x, xb, n8x, ef, efB, n8e, (unsigned*)invg, nz);

    TpTab tt;
    tt.d[0]  = {Wm[0], WxT0,  32,  64,  32,   0};
    tt.d[1]  = {Wm[1], WxT1,  64, 128,  64,   0};
    tt.d[2]  = {Wm[2], WxT2, 128, 128, 128,   0};
    tt.d[3]  = {Wm[3], WxT3, 128, 256, 128,   0};
    tt.d[4]  = {Wm[0], WeT0,  16,  64,  32,  32};
    tt.d[5]  = {Wm[1], WeT1,  16, 128,  32,  64};
    tt.d[6]  = {Wm[2], WeT2,  16, 128,  32, 128};
    tt.d[7]  = {Wm[3], WeT3,  16, 256,  32, 128};
    tt.d[8]  = {Ws[0], WsT0,  32,  64,  32,   0};
    tt.d[9]  = {Ws[1], WsT1,  64, 128,  64,   0};
    tt.d[10] = {Ws[2], WsT2, 128, 128, 128,   0};
    tt.d[11] = {Ws[3], WsT3, 128, 256, 128,   0};
    tp_all<<<dim3(256, 12), 256, 0, stream>>>(tt);

    // ---- sort edges by dst (rank-memoized counting sort) ----
    hist_cnt<<<EB + SCB, 256, 0, stream>>>(dst, hist, rankA, gid, invg);
    scanA<<<SCB, 256, 0, stream>>>(hist, bsum);
    scanB<<<1, 256, 0, stream>>>(bsum, boff);
    scanC<<<SCB, 256, 0, stream>>>(hist, boff, cursor, invdeg, invg, score,
                                   bc[0], bc[1], bc[2], bc[3]);
    scatter_kernel<<<EB, 256, 0, stream>>>(src, dst, cursor, rankA, efB, srcS, dstS, efS);

    const int NB = NP / 64;            // 782

    // layer 0: fin=32, f=64  (CW=64, 2-wave blocks EPB=128; CB=64)
    nodeP<32, 64, 64><<<dim3(NB, 1), 256, 0, stream>>>(xb, WxT0, P, agg);
    edge_q<64><<<EE / 128, 128, 0, stream>>>(efS, srcS, dstS, WeT0, P, bm[0], agg);
    node_mfma<32, 64, 64><<<dim3(NB, 1), 256, 0, stream>>>(xb, agg, WsT0, bs[0], Wc[0], invdeg, f1, rd);

    // layer 1: fin=64, f=128  (CW=128, EPB=128; CB=64)
    nodeP<64, 128, 64><<<dim3(NB, 2), 256, 0, stream>>>(f1, WxT1, P, agg);
    edge_q<128><<<EE / 128, 128, 0, stream>>>(efS, srcS, dstS, WeT1, P, bm[1], agg);
    node_mfma<64, 128, 64><<<dim3(NB, 2), 256, 0, stream>>>(f1, agg, WsT1, bs[1], Wc[1], invdeg, f2, rd);

    // layer 2: fin=128, f=128  (CW=128, EPB=128; CB=64)
    nodeP<128, 128, 64><<<dim3(NB, 2), 256, 0, stream>>>(f2, WxT2, P, agg);
    edge_q<128><<<EE / 128, 128, 0, stream>>>(efS, srcS, dstS, WeT2, P, bm[2], agg);
    node_mfma<128, 128, 64><<<dim3(NB, 2), 256, 0, stream>>>(f2, agg, WsT2, bs[2], Wc[2], invdeg, f3, rd);

    // layer 3: fin=128, f=256  (CW=128, WPG=2, EPB=64; CB=64)
    nodeP<128, 256, 64><<<dim3(NB, 4), 256, 0, stream>>>(f3, WxT3, P, agg);
    edge_q<256><<<EE / 64, 128, 0, stream>>>(efS, srcS, dstS, WeT3, P, bm[3], agg);
    node_mfma<128, 256, 64><<<dim3(NB, 4), 256, 0, stream>>>(f3, agg, WsT3, bs[3], Wc[3], invdeg, f4, rd);

    // final per-graph mean of accumulated classifier dots
    score_reduce<<<SCB, 256, 0, stream>>>(rd, gid, invg, score);
}